// Round 9
// baseline (193.378 us; speedup 1.0000x reference)
//
#include <hip/hip_runtime.h>

#define N_NODES 100000
#define N_EDGES 1600000
#define IN_CH 128
#define OUT_CH 64
#define BINSHIFT 9
#define BINSZ 512
#define NBINS 196          // ceil(100000/512)
#define CAP 16384          // slots per bin; bin load = 8192 +- 90, overflow ~0
#define PCHUNK 8192
#define PBLOCKS 200        // 200*8192 >= E
#define GEMM_BLOCKS ((N_NODES + 63) / 64)   // 1563 -> rows 0..100031
#define WT_LD 136          // padded k-stride (bf16 elems) for LDS W^T
#define ZROW N_NODES       // zeroed hp row for padding lanes

typedef __attribute__((ext_vector_type(8))) short bf16x8;
typedef __attribute__((ext_vector_type(4))) float f32x4;

__device__ __forceinline__ unsigned short f2bf(float f) {
    union { float f; unsigned u; } v; v.f = f;
    unsigned r = v.u + 0x7fffu + ((v.u >> 16) & 1u);   // rne
    return (unsigned short)(r >> 16);
}
__device__ __forceinline__ float bflo(unsigned u) {
    union { unsigned u; float f; } v; v.u = u << 16; return v.f;
}
__device__ __forceinline__ float bfhi(unsigned u) {
    union { unsigned u; float f; } v; v.u = u & 0xFFFF0000u; return v.f;
}

// ---------------- degree count: cnt[dst]++ (int atomics, L2-resident) ----------------
__global__ __launch_bounds__(256) void k_count(const int* __restrict__ dst,
                                               unsigned* __restrict__ cnt) {
    int e0 = (blockIdx.x * 256 + threadIdx.x) * 4;
    if (e0 < N_EDGES) {                   // N_EDGES % 4 == 0
        int4 d4 = *(const int4*)(dst + e0);
        atomicAdd(&cnt[d4.x], 1u);
        atomicAdd(&cnt[d4.y], 1u);
        atomicAdd(&cnt[d4.z], 1u);
        atomicAdd(&cnt[d4.w], 1u);
    }
}

// ---------------- fused: edge partition (blocks 0..199) + GEMM (rest) ----------------
__global__ __launch_bounds__(256) void k_pg(const int* __restrict__ src,
                                            const int* __restrict__ dst,
                                            unsigned* __restrict__ g_binptr,
                                            unsigned* __restrict__ part,
                                            const float* __restrict__ x,
                                            const float* __restrict__ Wmu,
                                            const float* __restrict__ Wls,
                                            const unsigned* __restrict__ cnt,
                                            unsigned short* __restrict__ hp) {
    __shared__ __align__(16) union {
        struct { unsigned hist[NBINS]; unsigned lbase[NBINS]; } p;
        unsigned short wt[128][WT_LD];                 // 34.8 KB
    } sm;
    int tid = threadIdx.x;

    if (blockIdx.x < PBLOCKS) {
        // ---------- partition role ----------
        if (tid < NBINS) sm.p.hist[tid] = 0;
        __syncthreads();
        int e0 = blockIdx.x * PCHUNK;
#pragma unroll 4
        for (int i = 0; i < PCHUNK / 256; ++i) {
            int e = e0 + i * 256 + tid;
            if (e < N_EDGES) atomicAdd(&sm.p.hist[dst[e] >> BINSHIFT], 1u);
        }
        __syncthreads();
        if (tid < NBINS) {
            unsigned h = sm.p.hist[tid];
            sm.p.lbase[tid] = (unsigned)tid * CAP + (h ? atomicAdd(&g_binptr[tid], h) : 0u);
            sm.p.hist[tid] = 0;
        }
        __syncthreads();
#pragma unroll 4
        for (int i = 0; i < PCHUNK / 256; ++i) {
            int e = e0 + i * 256 + tid;
            if (e < N_EDGES) {
                int d = dst[e];
                int bin = d >> BINSHIFT;
                unsigned pos = sm.p.lbase[bin] + atomicAdd(&sm.p.hist[bin], 1u);
                if (pos < ((unsigned)bin + 1u) * CAP)
                    part[pos] = (((unsigned)src[e]) << BINSHIFT) | (unsigned)(d & (BINSZ - 1));
            }
        }
        return;
    }

    // ---------- GEMM role: hp = bf16( dinv[row] * (x @ [W_mu|W_logstd]) ) ----------
    for (int f = tid; f < 8192; f += 256) {            // all 8192 elems per matrix
        int n = f & 63, k = f >> 6;
        sm.wt[n][k]      = f2bf(Wmu[f]);
        sm.wt[64 + n][k] = f2bf(Wls[f]);
    }
    __syncthreads();

    int gb   = blockIdx.x - PBLOCKS;
    int wid  = tid >> 6;               // 4 waves x 16 rows = 64 rows/block
    int lane = tid & 63;
    int wrow0 = gb * 64 + wid * 16;
    int m16  = lane & 15;
    int kgrp = lane >> 4;
    int koff = kgrp * 8;

    int lrow  = wrow0 + m16;
    int lrowc = lrow < N_NODES ? lrow : (N_NODES - 1);
    const float* xp = x + (size_t)lrowc * IN_CH + koff;

    f32x4 acc[8];
#pragma unroll
    for (int t = 0; t < 8; ++t) acc[t] = (f32x4){0.f, 0.f, 0.f, 0.f};

#pragma unroll
    for (int kb = 0; kb < 4; ++kb) {
        float4 x0 = *(const float4*)(xp + kb * 32);
        float4 x1 = *(const float4*)(xp + kb * 32 + 4);
        bf16x8 a;
        a[0] = (short)f2bf(x0.x); a[1] = (short)f2bf(x0.y);
        a[2] = (short)f2bf(x0.z); a[3] = (short)f2bf(x0.w);
        a[4] = (short)f2bf(x1.x); a[5] = (short)f2bf(x1.y);
        a[6] = (short)f2bf(x1.z); a[7] = (short)f2bf(x1.w);
#pragma unroll
        for (int t = 0; t < 8; ++t) {
            bf16x8 b = *(const bf16x8*)&sm.wt[t * 16 + m16][kb * 32 + koff];
            acc[t] = __builtin_amdgcn_mfma_f32_16x16x32_bf16(a, b, acc[t], 0, 0, 0);
        }
    }

    int r0 = wrow0 + kgrp * 4;         // D: col = lane&15, row = (lane>>4)*4 + reg
    float dvv[4];
#pragma unroll
    for (int r = 0; r < 4; ++r) {
        int rr = r0 + r;
        dvv[r] = (rr < N_NODES) ? rsqrtf((float)cnt[rr] + 1.0f) : 0.f;
    }
#pragma unroll
    for (int t = 0; t < 8; ++t) {
        int col = t * 16 + m16;
#pragma unroll
        for (int r = 0; r < 4; ++r) {
            int rr = r0 + r;
            if (rr < N_NODES + 32)     // pad rows (incl. ZROW) get zeros
                hp[(size_t)rr * 128 + col] = (rr < N_NODES) ? f2bf(acc[t][r] * dvv[r])
                                                            : (unsigned short)0;
        }
    }
}

// ---------------- per-bin CSR build in LDS; writes csr + rowptr ----------------
__global__ __launch_bounds__(512) void k_build(const unsigned* __restrict__ g_binptr,
                                               const unsigned* __restrict__ part,
                                               int* __restrict__ csr,
                                               unsigned* __restrict__ rowptr) {
    __shared__ unsigned hist[BINSZ];
    __shared__ unsigned ofs[BINSZ];
    __shared__ unsigned alloc_[BINSZ];
    __shared__ int csr_l[CAP];
    int tid = threadIdx.x;
    int b = blockIdx.x;
    unsigned base = (unsigned)b * CAP;
    unsigned cnt_b = g_binptr[b];
    if (cnt_b > CAP) cnt_b = CAP;

    hist[tid] = 0;
    __syncthreads();
    for (unsigned i = tid; i < cnt_b; i += 512)
        atomicAdd(&hist[part[base + i] & (BINSZ - 1)], 1u);
    __syncthreads();
    ofs[tid] = hist[tid];
    __syncthreads();
    for (int off = 1; off < BINSZ; off <<= 1) {
        unsigned v = (tid >= off) ? ofs[tid - off] : 0;
        __syncthreads();
        ofs[tid] += v;
        __syncthreads();
    }
    int d = b * BINSZ + tid;
    if (d < N_NODES)
        rowptr[d] = base + (ofs[tid] - hist[tid]);
    alloc_[tid] = 0;
    __syncthreads();
    for (unsigned i = tid; i < cnt_b; i += 512) {
        unsigned v = part[base + i];
        unsigned dl = v & (BINSZ - 1);
        unsigned p = (ofs[dl] - hist[dl]) + atomicAdd(&alloc_[dl], 1u);
        csr_l[p] = (int)(v >> BINSHIFT);
    }
    __syncthreads();
    for (unsigned i = tid; i < cnt_b; i += 512)
        csr[base + i] = csr_l[i];
}

// ---------------- gather: one wave per dst; scalar edge ids, 16 loads in flight ----------------
// out[d] = dv*( hp'[d] + sum_s hp'[s] ) + b   (hp' has dinv folded in)
__global__ __launch_bounds__(256) void k_gather(const unsigned* __restrict__ cnt,
                                                const unsigned* __restrict__ rowptr,
                                                const int* __restrict__ csr,
                                                const unsigned short* __restrict__ hp,
                                                const float* __restrict__ bmu,
                                                const float* __restrict__ bls,
                                                float* __restrict__ out) {
    int node = __builtin_amdgcn_readfirstlane(blockIdx.x * 4 + (threadIdx.x >> 6));
    if (node >= N_NODES) return;
    int lane = threadIdx.x & 63;
    int ch2  = lane * 2;                      // 2 channels per lane, 0..126

    int deg = (int)cnt[node];                 // scalar load (uniform addr)
    unsigned row = rowptr[node];

    float a0 = 0.f, a1 = 0.f;

    for (int i = 0; i < deg; i += 16) {
        unsigned u[16];
#pragma unroll
        for (int j = 0; j < 16; ++j) {
            int idx = i + j;
            int s = csr[row + idx];           // scalar load; safe OOB within csr buf
            s = (idx < deg) ? s : ZROW;       // s_cselect; pad -> zero row
            u[j] = *(const unsigned*)(hp + ((size_t)s << 7) + ch2);
        }
#pragma unroll
        for (int j = 0; j < 16; ++j) {
            a0 += bflo(u[j]);
            a1 += bfhi(u[j]);
        }
    }

    // self-loop
    unsigned su = *(const unsigned*)(hp + ((size_t)node << 7) + ch2);
    a0 += bflo(su);
    a1 += bfhi(su);

    float dv = rsqrtf((float)deg + 1.0f);
    float2 bv;
    float* op;
    if (lane < 32) {
        bv = *(const float2*)(bmu + ch2);
        op = out + (size_t)node * OUT_CH + ch2;
    } else {
        bv = *(const float2*)(bls + (ch2 - 64));
        op = out + (size_t)N_NODES * OUT_CH + (size_t)node * OUT_CH + (ch2 - 64);
    }
    __builtin_nontemporal_store(a0 * dv + bv.x, op);
    __builtin_nontemporal_store(a1 * dv + bv.y, op + 1);
}

extern "C" void kernel_launch(void* const* d_in, const int* in_sizes, int n_in,
                              void* d_out, int out_size, void* d_ws, size_t ws_size,
                              hipStream_t stream) {
    const float* x   = (const float*)d_in[0];
    const float* Wmu = (const float*)d_in[1];
    const float* bmu = (const float*)d_in[2];
    const float* Wls = (const float*)d_in[3];
    const float* bls = (const float*)d_in[4];
    const int*   ei  = (const int*)d_in[5];
    const int* src = ei;
    const int* dst = ei + N_EDGES;
    float* out = (float*)d_out;

    char* ws = (char*)d_ws;
    size_t off = 0;
    unsigned short* hp = (unsigned short*)(ws + off); off += (size_t)(N_NODES + 32) * 128 * 2;
    unsigned* part = (unsigned*)(ws + off);           off += (size_t)NBINS * CAP * 4;   // 12.8 MB
    int* csr = (int*)(ws + off);                      off += (size_t)NBINS * CAP * 4;   // 12.8 MB
    unsigned* rowptr = (unsigned*)(ws + off);         off += (size_t)N_NODES * 4;
    unsigned* cnt = (unsigned*)(ws + off);            off += (size_t)N_NODES * 4;
    unsigned* g_binptr = (unsigned*)(ws + off);       off += (size_t)NBINS * 4;
    // cnt and g_binptr contiguous -> single memset

    hipMemsetAsync(cnt, 0, (size_t)(N_NODES + NBINS) * sizeof(unsigned), stream);

    k_count <<<(N_EDGES / 4 + 255) / 256, 256, 0, stream>>>(dst, cnt);
    k_pg    <<<PBLOCKS + GEMM_BLOCKS, 256, 0, stream>>>(src, dst, g_binptr, part, x, Wmu, Wls, cnt, hp);
    k_build <<<NBINS, 512, 0, stream>>>(g_binptr, part, csr, rowptr);
    k_gather<<<(N_NODES + 3) / 4, 256, 0, stream>>>(cnt, rowptr, csr, hp, bmu, bls, out);
}

// Round 10
// 146.415 us; speedup vs baseline: 1.3208x; 1.3208x over previous
//
#include <hip/hip_runtime.h>

#define N_NODES 100000
#define N_EDGES 1600000
#define IN_CH 128
#define OUT_CH 64
#define BINSHIFT 9
#define BINSZ 512
#define NBINS 196          // ceil(100000/512)
#define CAP 16384          // slots per bin; bin load = 8192 +- 90, overflow ~0
#define PCHUNK 8192
#define PBLOCKS 200        // 200*8192 >= E
#define GEMM_BLOCKS ((N_NODES + 63) / 64)   // 1563 -> rows 0..100031
#define WT_LD 136          // padded k-stride (bf16 elems) for LDS W^T
#define ZROW N_NODES       // zeroed hp row for padding lanes

typedef __attribute__((ext_vector_type(8))) short bf16x8;
typedef __attribute__((ext_vector_type(4))) float f32x4;

__device__ __forceinline__ unsigned short f2bf(float f) {
    union { float f; unsigned u; } v; v.f = f;
    unsigned r = v.u + 0x7fffu + ((v.u >> 16) & 1u);   // rne
    return (unsigned short)(r >> 16);
}
__device__ __forceinline__ float bflo(unsigned u) {
    union { unsigned u; float f; } v; v.u = u << 16; return v.f;
}
__device__ __forceinline__ float bfhi(unsigned u) {
    union { unsigned u; float f; } v; v.u = u & 0xFFFF0000u; return v.f;
}

// ---------------- fused: edge partition (blocks 0..199) + GEMM (rest) ----------------
__global__ __launch_bounds__(256) void k_pg(const int* __restrict__ src,
                                            const int* __restrict__ dst,
                                            unsigned* __restrict__ g_binptr,
                                            unsigned* __restrict__ part,
                                            const float* __restrict__ x,
                                            const float* __restrict__ Wmu,
                                            const float* __restrict__ Wls,
                                            unsigned short* __restrict__ hp) {
    __shared__ __align__(16) union {
        struct { unsigned hist[NBINS]; unsigned lbase[NBINS]; } p;
        unsigned short wt[128][WT_LD];                 // 34.8 KB
    } sm;
    int tid = threadIdx.x;

    if (blockIdx.x < PBLOCKS) {
        // ---------- partition role ----------
        if (tid < NBINS) sm.p.hist[tid] = 0;
        __syncthreads();
        int e0 = blockIdx.x * PCHUNK;
#pragma unroll 4
        for (int i = 0; i < PCHUNK / 256; ++i) {
            int e = e0 + i * 256 + tid;
            if (e < N_EDGES) atomicAdd(&sm.p.hist[dst[e] >> BINSHIFT], 1u);
        }
        __syncthreads();
        if (tid < NBINS) {
            unsigned h = sm.p.hist[tid];
            sm.p.lbase[tid] = (unsigned)tid * CAP + (h ? atomicAdd(&g_binptr[tid], h) : 0u);
            sm.p.hist[tid] = 0;
        }
        __syncthreads();
#pragma unroll 4
        for (int i = 0; i < PCHUNK / 256; ++i) {
            int e = e0 + i * 256 + tid;
            if (e < N_EDGES) {
                int d = dst[e];
                int bin = d >> BINSHIFT;
                unsigned pos = sm.p.lbase[bin] + atomicAdd(&sm.p.hist[bin], 1u);
                if (pos < ((unsigned)bin + 1u) * CAP)
                    part[pos] = (((unsigned)src[e]) << BINSHIFT) | (unsigned)(d & (BINSZ - 1));
            }
        }
        return;
    }

    // ---------- GEMM role: hp = bf16(x @ [W_mu|W_logstd]), unscaled ----------
    for (int f = tid; f < 8192; f += 256) {            // all 8192 elems per matrix
        int n = f & 63, k = f >> 6;
        sm.wt[n][k]      = f2bf(Wmu[f]);
        sm.wt[64 + n][k] = f2bf(Wls[f]);
    }
    __syncthreads();

    int gb   = blockIdx.x - PBLOCKS;
    int wid  = tid >> 6;               // 4 waves x 16 rows = 64 rows/block
    int lane = tid & 63;
    int wrow0 = gb * 64 + wid * 16;
    int m16  = lane & 15;
    int kgrp = lane >> 4;
    int koff = kgrp * 8;

    int lrow  = wrow0 + m16;
    int lrowc = lrow < N_NODES ? lrow : (N_NODES - 1);
    const float* xp = x + (size_t)lrowc * IN_CH + koff;

    f32x4 acc[8];
#pragma unroll
    for (int t = 0; t < 8; ++t) acc[t] = (f32x4){0.f, 0.f, 0.f, 0.f};

#pragma unroll
    for (int kb = 0; kb < 4; ++kb) {
        float4 x0 = *(const float4*)(xp + kb * 32);
        float4 x1 = *(const float4*)(xp + kb * 32 + 4);
        bf16x8 a;
        a[0] = (short)f2bf(x0.x); a[1] = (short)f2bf(x0.y);
        a[2] = (short)f2bf(x0.z); a[3] = (short)f2bf(x0.w);
        a[4] = (short)f2bf(x1.x); a[5] = (short)f2bf(x1.y);
        a[6] = (short)f2bf(x1.z); a[7] = (short)f2bf(x1.w);
#pragma unroll
        for (int t = 0; t < 8; ++t) {
            bf16x8 b = *(const bf16x8*)&sm.wt[t * 16 + m16][kb * 32 + koff];
            acc[t] = __builtin_amdgcn_mfma_f32_16x16x32_bf16(a, b, acc[t], 0, 0, 0);
        }
    }

    int r0 = wrow0 + kgrp * 4;         // D: col = lane&15, row = (lane>>4)*4 + reg
#pragma unroll
    for (int t = 0; t < 8; ++t) {
        int col = t * 16 + m16;
#pragma unroll
        for (int r = 0; r < 4; ++r) {
            int rr = r0 + r;
            if (rr < N_NODES + 32)     // pad rows (incl. ZROW) get zeros
                hp[(size_t)rr * 128 + col] = (rr < N_NODES) ? f2bf(acc[t][r])
                                                            : (unsigned short)0;
        }
    }
}

// ---- per-bin CSR build + packed rowdeg + in-place dinv scaling of hp ----
__global__ __launch_bounds__(512) void k_build(const unsigned* __restrict__ g_binptr,
                                               const unsigned* __restrict__ part,
                                               int* __restrict__ csr,
                                               unsigned* __restrict__ rowdeg,
                                               unsigned short* __restrict__ hp) {
    __shared__ unsigned hist[BINSZ];
    __shared__ unsigned ofs[BINSZ];
    __shared__ unsigned alloc_[BINSZ];
    __shared__ int csr_l[CAP];
    int tid = threadIdx.x;
    int b = blockIdx.x;
    unsigned base = (unsigned)b * CAP;
    unsigned cnt_b = g_binptr[b];
    if (cnt_b > CAP) cnt_b = CAP;

    hist[tid] = 0;
    __syncthreads();
    for (unsigned i = tid; i < cnt_b; i += 512)
        atomicAdd(&hist[part[base + i] & (BINSZ - 1)], 1u);
    __syncthreads();
    ofs[tid] = hist[tid];
    __syncthreads();
    for (int off = 1; off < BINSZ; off <<= 1) {
        unsigned v = (tid >= off) ? ofs[tid - off] : 0;
        __syncthreads();
        ofs[tid] += v;
        __syncthreads();
    }
    int d = b * BINSZ + tid;
    unsigned dg = hist[tid];
    if (d < N_NODES) {
        unsigned dgc = dg > 1023u ? 1023u : dg;        // statistically never capped
        rowdeg[d] = (base + (ofs[tid] - dg)) | (dgc << 22);
    }
    alloc_[tid] = 0;
    __syncthreads();
    for (unsigned i = tid; i < cnt_b; i += 512) {
        unsigned v = part[base + i];
        unsigned dl = v & (BINSZ - 1);
        unsigned p = (ofs[dl] - hist[dl]) + atomicAdd(&alloc_[dl], 1u);
        csr_l[p] = (int)(v >> BINSHIFT);
    }
    __syncthreads();                                   // csr_l complete; ofs dead
    ofs[tid] = __float_as_uint(rsqrtf((float)dg + 1.0f));
    __syncthreads();                                   // dinv table ready
    for (unsigned i = tid; i < cnt_b; i += 512)
        csr[base + i] = csr_l[i];                      // coalesced writeout
    // scale hp rows of this bin: hp[d] *= dinv[d]  (512 rows x 64 dwords)
    unsigned* hpw = (unsigned*)hp;
    for (int i = tid; i < BINSZ * 64; i += 512) {
        int rl = i >> 6;
        int dd = b * BINSZ + rl;
        if (dd < N_NODES) {
            float dvl = __uint_as_float(ofs[rl]);
            size_t idx = ((size_t)dd << 6) + (i & 63);
            unsigned u = hpw[idx];
            hpw[idx] = (unsigned)f2bf(bflo(u) * dvl)
                     | ((unsigned)f2bf(bfhi(u) * dvl) << 16);
        }
    }
}

// ---------------- gather: 1 wave/node; 4 edges per uint4 load ----------------
// out[d] = dv*( hp'[d] + sum_s hp'[s] ) + b   (hp' = dinv*h, pre-scaled)
__global__ __launch_bounds__(256) void k_gather(const unsigned* __restrict__ rowdeg,
                                                const int* __restrict__ csr,
                                                const unsigned short* __restrict__ hp,
                                                const float* __restrict__ bmu,
                                                const float* __restrict__ bls,
                                                float* __restrict__ out) {
    int node = blockIdx.x * 4 + (threadIdx.x >> 6);
    if (node >= N_NODES) return;
    int lane = threadIdx.x & 63;
    int eg = lane >> 4;                 // edge slot 0..3
    int q  = lane & 15;                 // quarter-row: dwords q*4..q*4+3 = ch q*8..q*8+7

    unsigned pk = rowdeg[node];         // wave-uniform -> scalar load
    int deg = (int)(pk >> 22);
    unsigned row = pk & 0x3FFFFFu;
    const unsigned* hpw = (const unsigned*)hp;

    float a0=0.f,a1=0.f,a2=0.f,a3=0.f,a4=0.f,a5=0.f,a6=0.f,a7=0.f;

    for (int i = 0; i < deg; i += 16) {
        uint4 v[4];
#pragma unroll
        for (int j = 0; j < 4; ++j) {
            int idx = i + j * 4 + eg;
            int s = __builtin_nontemporal_load(csr + row + idx);  // in-bin, safe
            s = (idx < deg) ? s : ZROW;
            v[j] = *(const uint4*)(hpw + ((size_t)s << 6) + q * 4);
        }
#pragma unroll
        for (int j = 0; j < 4; ++j) {
            a0 += bflo(v[j].x); a1 += bfhi(v[j].x);
            a2 += bflo(v[j].y); a3 += bfhi(v[j].y);
            a4 += bflo(v[j].z); a5 += bfhi(v[j].z);
            a6 += bflo(v[j].w); a7 += bfhi(v[j].w);
        }
    }

    // reduce across the 4 edge slots (lanes q, q+16, q+32, q+48)
    a0 += __shfl_xor(a0, 16); a0 += __shfl_xor(a0, 32);
    a1 += __shfl_xor(a1, 16); a1 += __shfl_xor(a1, 32);
    a2 += __shfl_xor(a2, 16); a2 += __shfl_xor(a2, 32);
    a3 += __shfl_xor(a3, 16); a3 += __shfl_xor(a3, 32);
    a4 += __shfl_xor(a4, 16); a4 += __shfl_xor(a4, 32);
    a5 += __shfl_xor(a5, 16); a5 += __shfl_xor(a5, 32);
    a6 += __shfl_xor(a6, 16); a6 += __shfl_xor(a6, 32);
    a7 += __shfl_xor(a7, 16); a7 += __shfl_xor(a7, 32);

    if (eg == 0) {
        uint4 sv = *(const uint4*)(hpw + ((size_t)node << 6) + q * 4);  // self-loop
        a0 += bflo(sv.x); a1 += bfhi(sv.x);
        a2 += bflo(sv.y); a3 += bfhi(sv.y);
        a4 += bflo(sv.z); a5 += bfhi(sv.z);
        a6 += bflo(sv.w); a7 += bfhi(sv.w);

        float dv = rsqrtf((float)deg + 1.0f);
        const float* bp; float* op;
        if (q < 8) { bp = bmu + q * 8;        op = out + (size_t)node * OUT_CH + q * 8; }
        else       { bp = bls + (q - 8) * 8;  op = out + (size_t)N_NODES * OUT_CH
                                                   + (size_t)node * OUT_CH + (q - 8) * 8; }
        float4 b0 = ((const float4*)bp)[0];
        float4 b1 = ((const float4*)bp)[1];
        __builtin_nontemporal_store(a0 * dv + b0.x, op + 0);
        __builtin_nontemporal_store(a1 * dv + b0.y, op + 1);
        __builtin_nontemporal_store(a2 * dv + b0.z, op + 2);
        __builtin_nontemporal_store(a3 * dv + b0.w, op + 3);
        __builtin_nontemporal_store(a4 * dv + b1.x, op + 4);
        __builtin_nontemporal_store(a5 * dv + b1.y, op + 5);
        __builtin_nontemporal_store(a6 * dv + b1.z, op + 6);
        __builtin_nontemporal_store(a7 * dv + b1.w, op + 7);
    }
}

extern "C" void kernel_launch(void* const* d_in, const int* in_sizes, int n_in,
                              void* d_out, int out_size, void* d_ws, size_t ws_size,
                              hipStream_t stream) {
    const float* x   = (const float*)d_in[0];
    const float* Wmu = (const float*)d_in[1];
    const float* bmu = (const float*)d_in[2];
    const float* Wls = (const float*)d_in[3];
    const float* bls = (const float*)d_in[4];
    const int*   ei  = (const int*)d_in[5];
    const int* src = ei;
    const int* dst = ei + N_EDGES;
    float* out = (float*)d_out;

    char* ws = (char*)d_ws;
    size_t off = 0;
    unsigned short* hp = (unsigned short*)(ws + off); off += (size_t)(N_NODES + 32) * 128 * 2;
    unsigned* part = (unsigned*)(ws + off);           off += (size_t)NBINS * CAP * 4;   // 12.8 MB
    int* csr = (int*)(ws + off);                      off += (size_t)NBINS * CAP * 4;   // 12.8 MB
    unsigned* rowdeg = (unsigned*)(ws + off);         off += (size_t)N_NODES * 4;
    unsigned* g_binptr = (unsigned*)(ws + off);       off += (size_t)NBINS * 4;

    hipMemsetAsync(g_binptr, 0, (size_t)NBINS * sizeof(unsigned), stream);

    k_pg    <<<PBLOCKS + GEMM_BLOCKS, 256, 0, stream>>>(src, dst, g_binptr, part, x, Wmu, Wls, hp);
    k_build <<<NBINS, 512, 0, stream>>>(g_binptr, part, csr, rowdeg, hp);
    k_gather<<<(N_NODES + 3) / 4, 256, 0, stream>>>(rowdeg, csr, hp, bmu, bls, out);
}

// Round 11
// 117.406 us; speedup vs baseline: 1.6471x; 1.2471x over previous
//
#include <hip/hip_runtime.h>

#define N_NODES 100000
#define N_EDGES 1600000
#define IN_CH 128
#define OUT_CH 64
#define BINSHIFT 9
#define BINSZ 512
#define NBINS 196          // ceil(100000/512)
#define CAP 16384          // slots per bin; bin load = 8192 +- 90, overflow ~0
#define PCHUNK 8192
#define PBLOCKS 196        // 196*8192 = 1,605,632 >= E
#define GEMM_BLOCKS ((N_NODES + 63) / 64)   // 1563 -> rows 0..100031
#define WT_LD 136          // padded k-stride (bf16 elems) for LDS W^T
#define ZROW N_NODES       // zeroed hp row / zero dinv slot for padding lanes

typedef __attribute__((ext_vector_type(8))) short bf16x8;
typedef __attribute__((ext_vector_type(4))) float f32x4;

__device__ __forceinline__ unsigned short f2bf(float f) {
    union { float f; unsigned u; } v; v.f = f;
    unsigned r = v.u + 0x7fffu + ((v.u >> 16) & 1u);   // rne
    return (unsigned short)(r >> 16);
}
__device__ __forceinline__ float bflo(unsigned u) {
    union { unsigned u; float f; } v; v.u = u << 16; return v.f;
}
__device__ __forceinline__ float bfhi(unsigned u) {
    union { unsigned u; float f; } v; v.u = u & 0xFFFF0000u; return v.f;
}

// ---------------- fused: edge partition (blocks 0..195) + GEMM (rest) ----------------
__global__ __launch_bounds__(256) void k_pg(const int* __restrict__ src,
                                            const int* __restrict__ dst,
                                            unsigned* __restrict__ g_binptr,
                                            unsigned* __restrict__ part,
                                            const float* __restrict__ x,
                                            const float* __restrict__ Wmu,
                                            const float* __restrict__ Wls,
                                            unsigned short* __restrict__ hp) {
    __shared__ __align__(16) union {
        struct { unsigned hist[NBINS]; unsigned lbase[NBINS]; } p;
        unsigned short wt[128][WT_LD];                 // 34.8 KB
    } sm;
    int tid = threadIdx.x;

    if (blockIdx.x < PBLOCKS) {
        // ---------- partition role ----------
        if (tid < NBINS) sm.p.hist[tid] = 0;
        __syncthreads();
        const int4* dst4 = (const int4*)dst;
        const int4* src4 = (const int4*)src;
        int b4 = blockIdx.x * (PCHUNK / 4);            // int4 units
#pragma unroll
        for (int i = 0; i < PCHUNK / 4 / 256; ++i) {   // 8 iters
            int i4 = b4 + i * 256 + tid;
            if (i4 * 4 < N_EDGES) {                    // N_EDGES % 4 == 0
                int4 d4 = dst4[i4];
                atomicAdd(&sm.p.hist[d4.x >> BINSHIFT], 1u);
                atomicAdd(&sm.p.hist[d4.y >> BINSHIFT], 1u);
                atomicAdd(&sm.p.hist[d4.z >> BINSHIFT], 1u);
                atomicAdd(&sm.p.hist[d4.w >> BINSHIFT], 1u);
            }
        }
        __syncthreads();
        if (tid < NBINS) {
            unsigned h = sm.p.hist[tid];
            sm.p.lbase[tid] = (unsigned)tid * CAP + (h ? atomicAdd(&g_binptr[tid], h) : 0u);
            sm.p.hist[tid] = 0;                        // reuse as local allocator
        }
        __syncthreads();
#pragma unroll
        for (int i = 0; i < PCHUNK / 4 / 256; ++i) {
            int i4 = b4 + i * 256 + tid;
            if (i4 * 4 < N_EDGES) {
                int4 d4 = dst4[i4];
                int4 s4 = src4[i4];
#pragma unroll
                for (int c = 0; c < 4; ++c) {
                    int d = (&d4.x)[c];
                    int s = (&s4.x)[c];
                    int bin = d >> BINSHIFT;
                    unsigned pos = sm.p.lbase[bin] + atomicAdd(&sm.p.hist[bin], 1u);
                    if (pos < ((unsigned)bin + 1u) * CAP)   // statistical never-false
                        part[pos] = (((unsigned)s) << BINSHIFT) | (unsigned)(d & (BINSZ - 1));
                }
            }
        }
        return;
    }

    // ---------- GEMM role: hp = bf16(x @ [W_mu|W_logstd]), unscaled ----------
    for (int f = tid; f < 8192; f += 256) {            // all 8192 elems per matrix
        int n = f & 63, k = f >> 6;
        sm.wt[n][k]      = f2bf(Wmu[f]);
        sm.wt[64 + n][k] = f2bf(Wls[f]);
    }
    __syncthreads();

    int gb   = blockIdx.x - PBLOCKS;
    int wid  = tid >> 6;               // 4 waves x 16 rows = 64 rows/block
    int lane = tid & 63;
    int wrow0 = gb * 64 + wid * 16;
    int m16  = lane & 15;
    int kgrp = lane >> 4;
    int koff = kgrp * 8;

    int lrow  = wrow0 + m16;
    int lrowc = lrow < N_NODES ? lrow : (N_NODES - 1);
    const float* xp = x + (size_t)lrowc * IN_CH + koff;

    f32x4 acc[8];
#pragma unroll
    for (int t = 0; t < 8; ++t) acc[t] = (f32x4){0.f, 0.f, 0.f, 0.f};

#pragma unroll
    for (int kb = 0; kb < 4; ++kb) {
        float4 x0 = *(const float4*)(xp + kb * 32);
        float4 x1 = *(const float4*)(xp + kb * 32 + 4);
        bf16x8 a;
        a[0] = (short)f2bf(x0.x); a[1] = (short)f2bf(x0.y);
        a[2] = (short)f2bf(x0.z); a[3] = (short)f2bf(x0.w);
        a[4] = (short)f2bf(x1.x); a[5] = (short)f2bf(x1.y);
        a[6] = (short)f2bf(x1.z); a[7] = (short)f2bf(x1.w);
#pragma unroll
        for (int t = 0; t < 8; ++t) {
            bf16x8 b = *(const bf16x8*)&sm.wt[t * 16 + m16][kb * 32 + koff];
            acc[t] = __builtin_amdgcn_mfma_f32_16x16x32_bf16(a, b, acc[t], 0, 0, 0);
        }
    }

    int r0 = wrow0 + kgrp * 4;         // D: col = lane&15, row = (lane>>4)*4 + reg
#pragma unroll
    for (int t = 0; t < 8; ++t) {
        int col = t * 16 + m16;
#pragma unroll
        for (int r = 0; r < 4; ++r) {
            int rr = r0 + r;
            if (rr < N_NODES + 32)     // pad rows (incl. ZROW) get zeros
                hp[(size_t)rr * 128 + col] = (rr < N_NODES) ? f2bf(acc[t][r])
                                                            : (unsigned short)0;
        }
    }
}

// ---- per-bin CSR build (LDS) + packed rowdeg + dinv table ----
__global__ __launch_bounds__(512) void k_build(const unsigned* __restrict__ g_binptr,
                                               const unsigned* __restrict__ part,
                                               int* __restrict__ csr,
                                               unsigned* __restrict__ rowdeg,
                                               float* __restrict__ dinv) {
    __shared__ unsigned hist[BINSZ];
    __shared__ unsigned ofs[BINSZ];
    __shared__ unsigned alloc_[BINSZ];
    __shared__ int csr_l[CAP];
    int tid = threadIdx.x;
    int b = blockIdx.x;
    unsigned base = (unsigned)b * CAP;
    unsigned cnt_b = g_binptr[b];
    if (cnt_b > CAP) cnt_b = CAP;

    hist[tid] = 0;
    __syncthreads();
    // histogram of dlow, uint4-vectorized
    {
        const uint4* p4 = (const uint4*)(part + base);
        unsigned c4 = cnt_b >> 2;
        for (unsigned i = tid; i < c4; i += 512) {
            uint4 v = p4[i];
            atomicAdd(&hist[v.x & (BINSZ - 1)], 1u);
            atomicAdd(&hist[v.y & (BINSZ - 1)], 1u);
            atomicAdd(&hist[v.z & (BINSZ - 1)], 1u);
            atomicAdd(&hist[v.w & (BINSZ - 1)], 1u);
        }
        for (unsigned i = (c4 << 2) + tid; i < cnt_b; i += 512)
            atomicAdd(&hist[part[base + i] & (BINSZ - 1)], 1u);
    }
    __syncthreads();
    ofs[tid] = hist[tid];
    __syncthreads();
    for (int off = 1; off < BINSZ; off <<= 1) {        // inclusive scan
        unsigned v = (tid >= off) ? ofs[tid - off] : 0;
        __syncthreads();
        ofs[tid] += v;
        __syncthreads();
    }
    int d = b * BINSZ + tid;
    unsigned dg = hist[tid];
    if (d < N_NODES) {
        unsigned dgc = dg > 1023u ? 1023u : dg;        // statistically never capped
        rowdeg[d] = (base + (ofs[tid] - dg)) | (dgc << 22);
        dinv[d] = rsqrtf((float)dg + 1.0f);
    }
    if (b == 0 && tid == 0) dinv[ZROW] = 0.f;          // pad-slot weight
    alloc_[tid] = 0;
    __syncthreads();
    for (unsigned i = tid; i < cnt_b; i += 512) {
        unsigned v = part[base + i];
        unsigned dl = v & (BINSZ - 1);
        unsigned p = (ofs[dl] - hist[dl]) + atomicAdd(&alloc_[dl], 1u);
        csr_l[p] = (int)(v >> BINSHIFT);
    }
    __syncthreads();
    // coalesced uint4 writeout
    {
        uint4* c4o = (uint4*)(csr + base);
        const uint4* c4i = (const uint4*)csr_l;
        unsigned c4 = cnt_b >> 2;
        for (unsigned i = tid; i < c4; i += 512)
            c4o[i] = c4i[i];
        for (unsigned i = (c4 << 2) + tid; i < cnt_b; i += 512)
            csr[base + i] = csr_l[i];
    }
}

// ---------------- gather: 1 wave/node; 4 edges per uint4 load; inline dinv weights ----------------
// out[d] = dv*( sum_s dinv[s]*h[s] + dv*h[d] ) + b
__global__ __launch_bounds__(256) void k_gather(const unsigned* __restrict__ rowdeg,
                                                const int* __restrict__ csr,
                                                const float* __restrict__ dinv,
                                                const unsigned short* __restrict__ hp,
                                                const float* __restrict__ bmu,
                                                const float* __restrict__ bls,
                                                float* __restrict__ out) {
    int node = blockIdx.x * 4 + (threadIdx.x >> 6);
    if (node >= N_NODES) return;
    int lane = threadIdx.x & 63;
    int eg = lane >> 4;                 // edge slot 0..3
    int q  = lane & 15;                 // quarter-row: dwords q*4..q*4+3 = ch q*8..q*8+7

    unsigned pk = rowdeg[node];         // wave-uniform
    int deg = (int)(pk >> 22);
    unsigned row = pk & 0x3FFFFFu;
    const unsigned* hpw = (const unsigned*)hp;

    float a0=0.f,a1=0.f,a2=0.f,a3=0.f,a4=0.f,a5=0.f,a6=0.f,a7=0.f;

    for (int i = 0; i < deg; i += 16) {
        uint4 v[4]; float w[4];
#pragma unroll
        for (int j = 0; j < 4; ++j) {
            int idx = i + j * 4 + eg;
            int s = __builtin_nontemporal_load(csr + row + idx);  // in-buffer, safe
            s = (idx < deg) ? s : ZROW;
            w[j] = dinv[s];                              // dinv[ZROW]=0 kills pad terms
            v[j] = *(const uint4*)(hpw + ((size_t)s << 6) + q * 4);
        }
#pragma unroll
        for (int j = 0; j < 4; ++j) {
            a0 += w[j] * bflo(v[j].x); a1 += w[j] * bfhi(v[j].x);
            a2 += w[j] * bflo(v[j].y); a3 += w[j] * bfhi(v[j].y);
            a4 += w[j] * bflo(v[j].z); a5 += w[j] * bfhi(v[j].z);
            a6 += w[j] * bflo(v[j].w); a7 += w[j] * bfhi(v[j].w);
        }
    }

    // reduce across the 4 edge slots (lanes q, q+16, q+32, q+48)
    a0 += __shfl_xor(a0, 16); a0 += __shfl_xor(a0, 32);
    a1 += __shfl_xor(a1, 16); a1 += __shfl_xor(a1, 32);
    a2 += __shfl_xor(a2, 16); a2 += __shfl_xor(a2, 32);
    a3 += __shfl_xor(a3, 16); a3 += __shfl_xor(a3, 32);
    a4 += __shfl_xor(a4, 16); a4 += __shfl_xor(a4, 32);
    a5 += __shfl_xor(a5, 16); a5 += __shfl_xor(a5, 32);
    a6 += __shfl_xor(a6, 16); a6 += __shfl_xor(a6, 32);
    a7 += __shfl_xor(a7, 16); a7 += __shfl_xor(a7, 32);

    if (eg == 0) {
        float dv = rsqrtf((float)deg + 1.0f);
        uint4 sv = *(const uint4*)(hpw + ((size_t)node << 6) + q * 4);  // self-loop
        a0 += dv * bflo(sv.x); a1 += dv * bfhi(sv.x);
        a2 += dv * bflo(sv.y); a3 += dv * bfhi(sv.y);
        a4 += dv * bflo(sv.z); a5 += dv * bfhi(sv.z);
        a6 += dv * bflo(sv.w); a7 += dv * bfhi(sv.w);

        const float* bp; float* op;
        if (q < 8) { bp = bmu + q * 8;        op = out + (size_t)node * OUT_CH + q * 8; }
        else       { bp = bls + (q - 8) * 8;  op = out + (size_t)N_NODES * OUT_CH
                                                   + (size_t)node * OUT_CH + (q - 8) * 8; }
        float4 b0 = ((const float4*)bp)[0];
        float4 b1 = ((const float4*)bp)[1];
        __builtin_nontemporal_store(a0 * dv + b0.x, op + 0);
        __builtin_nontemporal_store(a1 * dv + b0.y, op + 1);
        __builtin_nontemporal_store(a2 * dv + b0.z, op + 2);
        __builtin_nontemporal_store(a3 * dv + b0.w, op + 3);
        __builtin_nontemporal_store(a4 * dv + b1.x, op + 4);
        __builtin_nontemporal_store(a5 * dv + b1.y, op + 5);
        __builtin_nontemporal_store(a6 * dv + b1.z, op + 6);
        __builtin_nontemporal_store(a7 * dv + b1.w, op + 7);
    }
}

extern "C" void kernel_launch(void* const* d_in, const int* in_sizes, int n_in,
                              void* d_out, int out_size, void* d_ws, size_t ws_size,
                              hipStream_t stream) {
    const float* x   = (const float*)d_in[0];
    const float* Wmu = (const float*)d_in[1];
    const float* bmu = (const float*)d_in[2];
    const float* Wls = (const float*)d_in[3];
    const float* bls = (const float*)d_in[4];
    const int*   ei  = (const int*)d_in[5];
    const int* src = ei;
    const int* dst = ei + N_EDGES;
    float* out = (float*)d_out;

    char* ws = (char*)d_ws;
    size_t off = 0;
    unsigned short* hp = (unsigned short*)(ws + off); off += (size_t)(N_NODES + 32) * 128 * 2;
    unsigned* part = (unsigned*)(ws + off);           off += (size_t)NBINS * CAP * 4;   // 12.8 MB
    int* csr = (int*)(ws + off);                      off += (size_t)NBINS * CAP * 4;   // 12.8 MB
    unsigned* rowdeg = (unsigned*)(ws + off);         off += (size_t)N_NODES * 4;
    float* dinv = (float*)(ws + off);                 off += (size_t)(N_NODES + 1) * 4;
    unsigned* g_binptr = (unsigned*)(ws + off);       off += (size_t)NBINS * 4;

    hipMemsetAsync(g_binptr, 0, (size_t)NBINS * sizeof(unsigned), stream);

    k_pg    <<<PBLOCKS + GEMM_BLOCKS, 256, 0, stream>>>(src, dst, g_binptr, part, x, Wmu, Wls, hp);
    k_build <<<NBINS, 512, 0, stream>>>(g_binptr, part, csr, rowdeg, dinv);
    k_gather<<<(N_NODES + 3) / 4, 256, 0, stream>>>(rowdeg, csr, dinv, hp, bmu, bls, out);
}

// Round 14
// 106.917 us; speedup vs baseline: 1.8087x; 1.0981x over previous
//
#include <hip/hip_runtime.h>

#define N_NODES 100000
#define N_EDGES 1600000
#define IN_CH 128
#define OUT_CH 64
#define BINSHIFT 9
#define BINSZ 512
#define NBINS 196          // ceil(100000/512)
#define CAP 16384          // slots per bin; bin load = 8192 +- 90, overflow ~0
#define PCHUNK 8192
#define PBLOCKS 196        // 196*8192 = 1,605,632 >= E
#define GEMM_BLOCKS ((N_NODES + 63) / 64)   // 1563 -> rows 0..100031
#define WT_LD 136          // padded k-stride (bf16 elems) for LDS W^T
#define ZROW N_NODES       // pad slot: wsc[ZROW]=0 kills its contributions

typedef __attribute__((ext_vector_type(8))) short bf16x8;
typedef __attribute__((ext_vector_type(4))) float f32x4;

__device__ __forceinline__ unsigned short f2bf(float f) {
    union { float f; unsigned u; } v; v.f = f;
    unsigned r = v.u + 0x7fffu + ((v.u >> 16) & 1u);   // rne
    return (unsigned short)(r >> 16);
}

// ---------------- fused: edge partition (blocks 0..195) + GEMM (rest) ----------------
__global__ __launch_bounds__(256) void k_pg(const int* __restrict__ src,
                                            const int* __restrict__ dst,
                                            unsigned* __restrict__ g_binptr,
                                            unsigned* __restrict__ part,
                                            const float* __restrict__ x,
                                            const float* __restrict__ Wmu,
                                            const float* __restrict__ Wls,
                                            signed char* __restrict__ hpq,
                                            float* __restrict__ sc) {
    __shared__ __align__(16) union {
        struct { unsigned hist[NBINS]; unsigned lbase[NBINS]; } p;
        unsigned short wt[128][WT_LD];                 // 34.8 KB
        signed char qt[64][128];                       // 8 KB, reused after wt is dead
    } sm;
    int tid = threadIdx.x;

    if (blockIdx.x < PBLOCKS) {
        // ---------- partition role ----------
        if (tid < NBINS) sm.p.hist[tid] = 0;
        __syncthreads();
        const int4* dst4 = (const int4*)dst;
        const int4* src4 = (const int4*)src;
        int b4 = blockIdx.x * (PCHUNK / 4);
#pragma unroll
        for (int i = 0; i < PCHUNK / 4 / 256; ++i) {
            int i4 = b4 + i * 256 + tid;
            if (i4 * 4 < N_EDGES) {
                int4 d4 = dst4[i4];
                atomicAdd(&sm.p.hist[d4.x >> BINSHIFT], 1u);
                atomicAdd(&sm.p.hist[d4.y >> BINSHIFT], 1u);
                atomicAdd(&sm.p.hist[d4.z >> BINSHIFT], 1u);
                atomicAdd(&sm.p.hist[d4.w >> BINSHIFT], 1u);
            }
        }
        __syncthreads();
        if (tid < NBINS) {
            unsigned h = sm.p.hist[tid];
            sm.p.lbase[tid] = (unsigned)tid * CAP + (h ? atomicAdd(&g_binptr[tid], h) : 0u);
            sm.p.hist[tid] = 0;
        }
        __syncthreads();
#pragma unroll
        for (int i = 0; i < PCHUNK / 4 / 256; ++i) {
            int i4 = b4 + i * 256 + tid;
            if (i4 * 4 < N_EDGES) {
                int4 d4 = dst4[i4];
                int4 s4 = src4[i4];
#pragma unroll
                for (int c = 0; c < 4; ++c) {
                    int d = (&d4.x)[c];
                    int s = (&s4.x)[c];
                    int bin = d >> BINSHIFT;
                    unsigned pos = sm.p.lbase[bin] + atomicAdd(&sm.p.hist[bin], 1u);
                    if (pos < ((unsigned)bin + 1u) * CAP)
                        part[pos] = (((unsigned)s) << BINSHIFT) | (unsigned)(d & (BINSZ - 1));
                }
            }
        }
        return;
    }

    // ---------- GEMM role: hpq = int8-rowquant(x @ [W_mu|W_logstd]), sc = absmax/127 ----------
    for (int f = tid; f < 8192; f += 256) {
        int n = f & 63, k = f >> 6;
        sm.wt[n][k]      = f2bf(Wmu[f]);
        sm.wt[64 + n][k] = f2bf(Wls[f]);
    }
    __syncthreads();

    int gb   = blockIdx.x - PBLOCKS;
    int wid  = tid >> 6;               // 4 waves x 16 rows = 64 rows/block
    int lane = tid & 63;
    int wrow0 = gb * 64 + wid * 16;
    int m16  = lane & 15;
    int kgrp = lane >> 4;
    int koff = kgrp * 8;

    int lrow  = wrow0 + m16;
    int lrowc = lrow < N_NODES ? lrow : (N_NODES - 1);
    const float* xp = x + (size_t)lrowc * IN_CH + koff;

    f32x4 acc[8];
#pragma unroll
    for (int t = 0; t < 8; ++t) acc[t] = (f32x4){0.f, 0.f, 0.f, 0.f};

#pragma unroll
    for (int kb = 0; kb < 4; ++kb) {
        float4 x0 = *(const float4*)(xp + kb * 32);
        float4 x1 = *(const float4*)(xp + kb * 32 + 4);
        bf16x8 a;
        a[0] = (short)f2bf(x0.x); a[1] = (short)f2bf(x0.y);
        a[2] = (short)f2bf(x0.z); a[3] = (short)f2bf(x0.w);
        a[4] = (short)f2bf(x1.x); a[5] = (short)f2bf(x1.y);
        a[6] = (short)f2bf(x1.z); a[7] = (short)f2bf(x1.w);
#pragma unroll
        for (int t = 0; t < 8; ++t) {
            bf16x8 b = *(const bf16x8*)&sm.wt[t * 16 + m16][kb * 32 + koff];
            acc[t] = __builtin_amdgcn_mfma_f32_16x16x32_bf16(a, b, acc[t], 0, 0, 0);
        }
    }

    // ---- epilogue: per-row int8 quantization ----
    // D layout: col = t*16 + m16, row = wrow0 + kgrp*4 + r
    int r0 = wrow0 + kgrp * 4;
    float rmax[4];
#pragma unroll
    for (int r = 0; r < 4; ++r) {
        float m = 0.f;
#pragma unroll
        for (int t = 0; t < 8; ++t) m = fmaxf(m, fabsf(acc[t][r]));
        rmax[r] = m;
    }
#pragma unroll
    for (int off = 1; off < 16; off <<= 1) {           // reduce across the 16 m16-lanes
#pragma unroll
        for (int r = 0; r < 4; ++r)
            rmax[r] = fmaxf(rmax[r], __shfl_xor(rmax[r], off));
    }
    float inv[4];
#pragma unroll
    for (int r = 0; r < 4; ++r)
        inv[r] = rmax[r] > 0.f ? 127.f / rmax[r] : 0.f;
    if (m16 == 0) {
#pragma unroll
        for (int r = 0; r < 4; ++r) {
            int rr = r0 + r;
            if (rr < N_NODES) sc[rr] = rmax[r] > 0.f ? rmax[r] / 127.f : 0.f;
        }
    }
    __syncthreads();                                   // wt reads done -> reuse as qt
    // each wave owns qt rows wid*16 .. wid*16+15 (= global rows gb*64 + wid*16 ...)
#pragma unroll
    for (int t = 0; t < 8; ++t) {
        int col = t * 16 + m16;
#pragma unroll
        for (int r = 0; r < 4; ++r) {
            float qf = fminf(fmaxf(acc[t][r] * inv[r], -127.f), 127.f);
            sm.qt[wid * 16 + kgrp * 4 + r][col] = (signed char)(int)rintf(qf);
        }
    }
    __syncthreads();
    // coalesced writeout: 64 rows x 128 B = 512 uint4, BLOCK base (bugfix r13->r14)
    {
        const uint4* qi4 = (const uint4*)sm.qt;
        uint4* ho = (uint4*)(hpq + (size_t)(gb * 64) * 128);
        ho[tid]       = qi4[tid];
        ho[tid + 256] = qi4[tid + 256];
    }
}

// ---- per-bin CSR build (LDS) + packed rowdeg + wsc = dinv*sc ----
__global__ __launch_bounds__(512) void k_build(const unsigned* __restrict__ g_binptr,
                                               const unsigned* __restrict__ part,
                                               int* __restrict__ csr,
                                               unsigned* __restrict__ rowdeg,
                                               const float* __restrict__ sc,
                                               float* __restrict__ wsc) {
    __shared__ unsigned hist[BINSZ];
    __shared__ unsigned ofs[BINSZ];
    __shared__ unsigned alloc_[BINSZ];
    __shared__ int csr_l[CAP];
    int tid = threadIdx.x;
    int b = blockIdx.x;
    unsigned base = (unsigned)b * CAP;
    unsigned cnt_b = g_binptr[b];
    if (cnt_b > CAP) cnt_b = CAP;

    hist[tid] = 0;
    __syncthreads();
    {
        const uint4* p4 = (const uint4*)(part + base);
        unsigned c4 = cnt_b >> 2;
        for (unsigned i = tid; i < c4; i += 512) {
            uint4 v = p4[i];
            atomicAdd(&hist[v.x & (BINSZ - 1)], 1u);
            atomicAdd(&hist[v.y & (BINSZ - 1)], 1u);
            atomicAdd(&hist[v.z & (BINSZ - 1)], 1u);
            atomicAdd(&hist[v.w & (BINSZ - 1)], 1u);
        }
        for (unsigned i = (c4 << 2) + tid; i < cnt_b; i += 512)
            atomicAdd(&hist[part[base + i] & (BINSZ - 1)], 1u);
    }
    __syncthreads();
    ofs[tid] = hist[tid];
    __syncthreads();
    for (int off = 1; off < BINSZ; off <<= 1) {
        unsigned v = (tid >= off) ? ofs[tid - off] : 0;
        __syncthreads();
        ofs[tid] += v;
        __syncthreads();
    }
    int d = b * BINSZ + tid;
    unsigned dg = hist[tid];
    if (d < N_NODES) {
        unsigned dgc = dg > 1023u ? 1023u : dg;
        rowdeg[d] = (base + (ofs[tid] - dg)) | (dgc << 22);
        wsc[d] = rsqrtf((float)dg + 1.0f) * sc[d];
    }
    if (b == 0 && tid == 0) wsc[ZROW] = 0.f;
    alloc_[tid] = 0;
    __syncthreads();
    for (unsigned i = tid; i < cnt_b; i += 512) {
        unsigned v = part[base + i];
        unsigned dl = v & (BINSZ - 1);
        unsigned p = (ofs[dl] - hist[dl]) + atomicAdd(&alloc_[dl], 1u);
        csr_l[p] = (int)(v >> BINSHIFT);
    }
    __syncthreads();
    {
        uint4* c4o = (uint4*)(csr + base);
        const uint4* c4i = (const uint4*)csr_l;
        unsigned c4 = cnt_b >> 2;
        for (unsigned i = tid; i < c4; i += 512)
            c4o[i] = c4i[i];
        for (unsigned i = (c4 << 2) + tid; i < cnt_b; i += 512)
            csr[base + i] = csr_l[i];
    }
}

// ---------------- gather: 1 wave/node; int8 rows, 4 edges/iter-group ----------------
// out[d] = dv*( sum_s wsc[s]*q_s + wsc[d]*q_d ) + b ,  wsc = dinv*scale
__global__ __launch_bounds__(256) void k_gather(const unsigned* __restrict__ rowdeg,
                                                const int* __restrict__ csr,
                                                const float* __restrict__ wsc,
                                                const signed char* __restrict__ hpq,
                                                const float* __restrict__ bmu,
                                                const float* __restrict__ bls,
                                                float* __restrict__ out) {
    int node = blockIdx.x * 4 + (threadIdx.x >> 6);
    if (node >= N_NODES) return;
    int lane = threadIdx.x & 63;
    int eg = lane >> 4;                 // edge slot 0..3
    int q  = lane & 15;                 // 8 channels: q*8 .. q*8+7

    unsigned pk = rowdeg[node];
    int deg = (int)(pk >> 22);
    unsigned row = pk & 0x3FFFFFu;

    float a0=0.f,a1=0.f,a2=0.f,a3=0.f,a4=0.f,a5=0.f,a6=0.f,a7=0.f;

    for (int i = 0; i < deg; i += 16) {
        uint2 v[4]; float w[4];
#pragma unroll
        for (int j = 0; j < 4; ++j) {
            int idx = i + j * 4 + eg;
            int s = __builtin_nontemporal_load(csr + row + idx);
            s = (idx < deg) ? s : ZROW;
            w[j] = wsc[s];                               // 0 for pad slot
            v[j] = *(const uint2*)(hpq + ((size_t)s << 7) + q * 8);
        }
#pragma unroll
        for (int j = 0; j < 4; ++j) {
            unsigned ux = v[j].x, uy = v[j].y;
            a0 += w[j] * (float)((int)(ux << 24) >> 24);
            a1 += w[j] * (float)((int)(ux << 16) >> 24);
            a2 += w[j] * (float)((int)(ux <<  8) >> 24);
            a3 += w[j] * (float)((int)(ux      ) >> 24);
            a4 += w[j] * (float)((int)(uy << 24) >> 24);
            a5 += w[j] * (float)((int)(uy << 16) >> 24);
            a6 += w[j] * (float)((int)(uy <<  8) >> 24);
            a7 += w[j] * (float)((int)(uy      ) >> 24);
        }
    }

    a0 += __shfl_xor(a0, 16); a0 += __shfl_xor(a0, 32);
    a1 += __shfl_xor(a1, 16); a1 += __shfl_xor(a1, 32);
    a2 += __shfl_xor(a2, 16); a2 += __shfl_xor(a2, 32);
    a3 += __shfl_xor(a3, 16); a3 += __shfl_xor(a3, 32);
    a4 += __shfl_xor(a4, 16); a4 += __shfl_xor(a4, 32);
    a5 += __shfl_xor(a5, 16); a5 += __shfl_xor(a5, 32);
    a6 += __shfl_xor(a6, 16); a6 += __shfl_xor(a6, 32);
    a7 += __shfl_xor(a7, 16); a7 += __shfl_xor(a7, 32);

    if (eg == 0) {
        float ws = wsc[node];                            // self-loop: dv*sc[d]
        uint2 sv = *(const uint2*)(hpq + ((size_t)node << 7) + q * 8);
        unsigned ux = sv.x, uy = sv.y;
        a0 += ws * (float)((int)(ux << 24) >> 24);
        a1 += ws * (float)((int)(ux << 16) >> 24);
        a2 += ws * (float)((int)(ux <<  8) >> 24);
        a3 += ws * (float)((int)(ux      ) >> 24);
        a4 += ws * (float)((int)(uy << 24) >> 24);
        a5 += ws * (float)((int)(uy << 16) >> 24);
        a6 += ws * (float)((int)(uy <<  8) >> 24);
        a7 += ws * (float)((int)(uy      ) >> 24);

        float dv = rsqrtf((float)deg + 1.0f);
        const float* bp; float* op;
        if (q < 8) { bp = bmu + q * 8;        op = out + (size_t)node * OUT_CH + q * 8; }
        else       { bp = bls + (q - 8) * 8;  op = out + (size_t)N_NODES * OUT_CH
                                                   + (size_t)node * OUT_CH + (q - 8) * 8; }
        float4 b0 = ((const float4*)bp)[0];
        float4 b1 = ((const float4*)bp)[1];
        __builtin_nontemporal_store(a0 * dv + b0.x, op + 0);
        __builtin_nontemporal_store(a1 * dv + b0.y, op + 1);
        __builtin_nontemporal_store(a2 * dv + b0.z, op + 2);
        __builtin_nontemporal_store(a3 * dv + b0.w, op + 3);
        __builtin_nontemporal_store(a4 * dv + b1.x, op + 4);
        __builtin_nontemporal_store(a5 * dv + b1.y, op + 5);
        __builtin_nontemporal_store(a6 * dv + b1.z, op + 6);
        __builtin_nontemporal_store(a7 * dv + b1.w, op + 7);
    }
}

extern "C" void kernel_launch(void* const* d_in, const int* in_sizes, int n_in,
                              void* d_out, int out_size, void* d_ws, size_t ws_size,
                              hipStream_t stream) {
    const float* x   = (const float*)d_in[0];
    const float* Wmu = (const float*)d_in[1];
    const float* bmu = (const float*)d_in[2];
    const float* Wls = (const float*)d_in[3];
    const float* bls = (const float*)d_in[4];
    const int*   ei  = (const int*)d_in[5];
    const int* src = ei;
    const int* dst = ei + N_EDGES;
    float* out = (float*)d_out;

    char* ws = (char*)d_ws;
    size_t off = 0;
    signed char* hpq = (signed char*)(ws + off);  off += (size_t)(N_NODES + 32) * 128;  // 12.8 MB
    unsigned* part = (unsigned*)(ws + off);       off += (size_t)NBINS * CAP * 4;       // 12.8 MB
    int* csr = (int*)(ws + off);                  off += (size_t)NBINS * CAP * 4;       // 12.8 MB
    unsigned* rowdeg = (unsigned*)(ws + off);     off += (size_t)N_NODES * 4;
    float* sc = (float*)(ws + off);               off += (size_t)N_NODES * 4;
    float* wsc = (float*)(ws + off);              off += (size_t)(N_NODES + 1) * 4;
    unsigned* g_binptr = (unsigned*)(ws + off);   off += (size_t)NBINS * 4;

    hipMemsetAsync(g_binptr, 0, (size_t)NBINS * sizeof(unsigned), stream);

    k_pg    <<<PBLOCKS + GEMM_BLOCKS, 256, 0, stream>>>(src, dst, g_binptr, part, x, Wmu, Wls, hpq, sc);
    k_build <<<NBINS, 512, 0, stream>>>(g_binptr, part, csr, rowdeg, sc, wsc);
    k_gather<<<(N_NODES + 3) / 4, 256, 0, stream>>>(rowdeg, csr, wsc, hpq, bmu, bls, out);
}